// Round 9
// baseline (139.197 us; speedup 1.0000x reference)
//
#include <hip/hip_runtime.h>

#define CUTOFF 5.0f
#define DEPS 1e-12f
#define FSQRT(x) __builtin_amdgcn_sqrtf(x)

// ws float layout (first 136 floats zeroed by hipMemsetAsync each launch):
//  ws[0]      ligand coord-loss sum of per-batch ratios
//  ws[1]      (as uint) done-block counter
//  ws[3..6]   sidechain mse, am, val, has sums
//  [8, 72)    bnum[64]  per-batch ligand pair num (triangular: half of ref sums)
//  [72, 136)  bden[64]  per-batch ligand pair den

#define NSC_BLK 512   // blocks [0,512): sidechain, 128 groups each (2 lanes/group)
#define NLIG_BLK 512  // blocks [512,1024): ligand, 64 batches * 8 balanced tile-pairs
#define GRID (NSC_BLK + NLIG_BLK)

__global__ __launch_bounds__(256) void fused_kernel(
    const float* __restrict__ lig_pred, const float* __restrict__ lig_tgt,
    const int* __restrict__ lig_mask,
    const float* __restrict__ sc_pred, const float* __restrict__ sc_tgt,
    const int* __restrict__ sc_mask,
    float* __restrict__ ws, float* __restrict__ out) {
  const int tid = threadIdx.x;
  float* bnum = ws + 8;
  float* bden = ws + 72;
  unsigned int* done = (unsigned int*)(ws + 1);

  __shared__ float4 stage4[1344];  // 21.5 KB; sc staging / ligand i-tiles (aliased)
  __shared__ float red[4][4];
  __shared__ bool last;

  if (blockIdx.x < NSC_BLK) {
    // ================= sidechain: 2 lanes per group (R4/R7 path, verified) =================
    const int sb = blockIdx.x;
    float ax[7], ay[7], az[7];  // pred, own atoms
    float bx[7], by[7], bz[7];  // tgt, own atoms
    float m[7];

    const float4* srcp = (const float4*)(sc_pred + (size_t)sb * 5376);
    for (int k = tid; k < 1344; k += 256) stage4[k] = srcp[k];
    __syncthreads();
    {
      const float* s = ((const float*)stage4) + tid * 21;  // gcd(21,32)=1: no conflicts
#pragma unroll
      for (int a = 0; a < 7; a++) { ax[a] = s[3 * a]; ay[a] = s[3 * a + 1]; az[a] = s[3 * a + 2]; }
    }
    __syncthreads();
    const float4* srct = (const float4*)(sc_tgt + (size_t)sb * 5376);
    for (int k = tid; k < 1344; k += 256) stage4[k] = srct[k];
    __syncthreads();
    {
      const float* s = ((const float*)stage4) + tid * 21;
#pragma unroll
      for (int a = 0; a < 7; a++) { bx[a] = s[3 * a]; by[a] = s[3 * a + 1]; bz[a] = s[3 * a + 2]; }
    }
    const int* mp = sc_mask + (size_t)sb * 1792 + tid * 7;
#pragma unroll
    for (int a = 0; a < 7; a++) m[a] = (mp[a] != 0) ? 1.f : 0.f;

    float mse = 0.f, am = 0.f;
#pragma unroll
    for (int a = 0; a < 7; a++) {
      float dx = ax[a] - bx[a], dy = ay[a] - by[a], dz = az[a] - bz[a];
      mse += m[a] * ((dx * dx + dy * dy + dz * dz) * (1.f / 3.f));
      am += m[a];
    }

    float num = 0.f, den = 0.f;
#pragma unroll
    for (int js = 0; js < 7; js++) {
#pragma unroll
      for (int side = 0; side < 2; side++) {
        float jx, jy, jz, kx, ky, kz, mj;
        if (side == 0) {
          jx = ax[js]; jy = ay[js]; jz = az[js];
          kx = bx[js]; ky = by[js]; kz = bz[js];
          mj = m[js];
        } else {
          jx = __shfl_xor(ax[js], 1, 64); jy = __shfl_xor(ay[js], 1, 64);
          jz = __shfl_xor(az[js], 1, 64);
          kx = __shfl_xor(bx[js], 1, 64); ky = __shfl_xor(by[js], 1, 64);
          kz = __shfl_xor(bz[js], 1, 64);
          mj = __shfl_xor(m[js], 1, 64);
        }
#pragma unroll
        for (int i = 0; i < 7; i++) {
          float dx = bx[i] - kx, dy = by[i] - ky, dz = bz[i] - kz;
          float tsq = dx * dx + dy * dy + dz * dz;
          float td = FSQRT(fmaxf(tsq, DEPS));
          float w = m[i] * mj;
          w = (tsq > 0.f) ? w : 0.f;
          w = (td <= CUTOFF) ? w : 0.f;
          float qx = ax[i] - jx, qy = ay[i] - jy, qz = az[i] - jz;
          float pd = FSQRT(fmaxf(qx * qx + qy * qy + qz * qz, DEPS));
          float d = pd - td;
          num += w * d * d;
          den += w;
        }
      }
    }
    float num_g = num + __shfl_xor(num, 1, 64);
    float den_g = den + __shfl_xor(den, 1, 64);
    float val = (den_g > 0.f) ? 0.5f * (num_g / fmaxf(den_g, 1.f)) : 0.f;
    float has = (den_g > 0.f) ? 0.5f : 0.f;

    for (int off = 32; off > 0; off >>= 1) {
      mse += __shfl_down(mse, off, 64);
      am += __shfl_down(am, off, 64);
      val += __shfl_down(val, off, 64);
      has += __shfl_down(has, off, 64);
    }
    int lane = tid & 63, wv = tid >> 6;
    if (lane == 0) { red[0][wv] = mse; red[1][wv] = am; red[2][wv] = val; red[3][wv] = has; }
    __syncthreads();
    if (tid == 0) {
      atomicAdd(&ws[3], red[0][0] + red[0][1] + red[0][2] + red[0][3]);
      atomicAdd(&ws[4], red[1][0] + red[1][1] + red[1][2] + red[1][3]);
      atomicAdd(&ws[5], red[2][0] + red[2][1] + red[2][2] + red[2][3]);
      atomicAdd(&ws[6], red[3][0] + red[3][1] + red[3][2] + red[3][3]);
    }
  } else {
    // ====== ligand (R7 verified): triangular + balanced tile-pairs {t, 15-t},
    //        LDS-staged i-tiles (broadcast ds_read_b128) ======
    const int L = 512;
    const int lb = blockIdx.x - NSC_BLK;  // 0..511
    const int b = lb >> 3;
    const int t = lb & 7;
    const int i0a = 32 * t;
    const int i0b = 32 * (15 - t);
    const float* pb = lig_pred + (size_t)b * L * 3;
    const float* tb = lig_tgt + (size_t)b * L * 3;
    const int* mb = lig_mask + (size_t)b * L;

    float4* st4 = stage4;       // [0,32): tileA tgt(+mask), [32,64): tileB tgt(+mask)
    float4* sp4 = stage4 + 64;  // [0,32): tileA pred,       [32,64): tileB pred

    if (tid < 128) {
      int which = tid >> 5;  // 0: A-tgt, 1: B-tgt, 2: A-pred, 3: B-pred
      int idx = tid & 31;
      int i = ((which & 1) ? i0b : i0a) + idx;
      if (which < 2) {
        st4[(which << 5) + idx] =
            make_float4(tb[3 * i], tb[3 * i + 1], tb[3 * i + 2], (mb[i] != 0) ? 1.f : 0.f);
      } else {
        sp4[((which & 1) << 5) + idx] =
            make_float4(pb[3 * i], pb[3 * i + 1], pb[3 * i + 2], 0.f);
      }
    }
    __syncthreads();

    // num,den accumulate exactly HALF of the reference's symmetric sums.
    float num0 = 0.f, den0 = 0.f, num1 = 0.f, den1 = 0.f, se = 0.f, cnt = 0.f;

    // ---- tileA: js in [i0a, 512) ----
#pragma unroll
    for (int k = 0; k < 2; k++) {
      const int js = i0a + (k << 8) + tid;
      if (js < L) {
        float pjx = pb[3 * js], pjy = pb[3 * js + 1], pjz = pb[3 * js + 2];
        float tjx = tb[3 * js], tjy = tb[3 * js + 1], tjz = tb[3 * js + 2];
        float mj = (mb[js] != 0) ? 1.f : 0.f;
        if (t == 0) {  // t==0: slots k=0,1 cover all 512 atoms exactly once
          float dx = pjx - tjx, dy = pjy - tjy, dz = pjz - tjz;
          se += mj * (dx * dx + dy * dy + dz * dz);
          cnt += mj;
        }
#pragma unroll 4
        for (int ii = 0; ii < 32; ii++) {
          float4 ti = st4[ii];
          float4 pi = sp4[ii];
          float w = (js > i0a + ii) ? ti.w * mj : 0.f;  // triangular gate
          float dx = ti.x - tjx, dy = ti.y - tjy, dz = ti.z - tjz;
          float tsq = dx * dx + dy * dy + dz * dz;
          float td = FSQRT(fmaxf(tsq, DEPS));
          w = (tsq > 0.f) ? w : 0.f;
          w = (td <= CUTOFF) ? w : 0.f;
          float qx = pi.x - pjx, qy = pi.y - pjy, qz = pi.z - pjz;
          float pd = FSQRT(fmaxf(qx * qx + qy * qy + qz * qz, DEPS));
          float d = pd - td;
          if (ii & 1) { num1 += w * d * d; den1 += w; }
          else        { num0 += w * d * d; den0 += w; }
        }
      }
    }

    // ---- tileB: js in [i0b, 512), count = 32+32t <= 256 (single slot) ----
    {
      const int js = i0b + tid;
      if (js < L) {
        float pjx = pb[3 * js], pjy = pb[3 * js + 1], pjz = pb[3 * js + 2];
        float tjx = tb[3 * js], tjy = tb[3 * js + 1], tjz = tb[3 * js + 2];
        float mj = (mb[js] != 0) ? 1.f : 0.f;
#pragma unroll 4
        for (int ii = 0; ii < 32; ii++) {
          float4 ti = st4[32 + ii];
          float4 pi = sp4[32 + ii];
          float w = (js > i0b + ii) ? ti.w * mj : 0.f;
          float dx = ti.x - tjx, dy = ti.y - tjy, dz = ti.z - tjz;
          float tsq = dx * dx + dy * dy + dz * dz;
          float td = FSQRT(fmaxf(tsq, DEPS));
          w = (tsq > 0.f) ? w : 0.f;
          w = (td <= CUTOFF) ? w : 0.f;
          float qx = pi.x - pjx, qy = pi.y - pjy, qz = pi.z - pjz;
          float pd = FSQRT(fmaxf(qx * qx + qy * qy + qz * qz, DEPS));
          float d = pd - td;
          if (ii & 1) { num1 += w * d * d; den1 += w; }
          else        { num0 += w * d * d; den0 += w; }
        }
      }
    }

    float num = num0 + num1, den = den0 + den1;
    for (int off = 32; off > 0; off >>= 1) {
      num += __shfl_down(num, off, 64);
      den += __shfl_down(den, off, 64);
      se += __shfl_down(se, off, 64);
      cnt += __shfl_down(cnt, off, 64);
    }
    int lane = tid & 63, wv = tid >> 6;
    if (lane == 0) { red[0][wv] = num; red[1][wv] = den; red[2][wv] = se; red[3][wv] = cnt; }
    __syncthreads();
    if (tid == 0) {
      atomicAdd(&bnum[b], red[0][0] + red[0][1] + red[0][2] + red[0][3]);
      atomicAdd(&bden[b], red[1][0] + red[1][1] + red[1][2] + red[1][3]);
      if (t == 0) {
        float se_t = red[2][0] + red[2][1] + red[2][2] + red[2][3];
        float cnt_t = red[3][0] + red[3][1] + red[3][2] + red[3][3];
        atomicAdd(&ws[0], se_t / (3.f * fmaxf(cnt_t, 1.f)));
      }
    }
  }

  // ---------------- last-block finalize (R3/R8-proven pattern) ----------------
  if (tid == 0) {
    __threadfence();
    unsigned int old = atomicAdd(done, 1u);
    last = (old == GRID - 1);
  }
  __syncthreads();
  if (last && tid < 64) {
    // atomic read-backs: device-scope coherent view of other blocks' adds
    float n = atomicAdd(&bnum[tid], 0.f);
    float d = atomicAdd(&bden[tid], 0.f);
    float val = (d > 0.f) ? n / fmaxf(d, 1.f) : 0.f;
    float has = (d > 0.f) ? 1.f : 0.f;
    for (int off = 32; off > 0; off >>= 1) {
      val += __shfl_down(val, off, 64);
      has += __shfl_down(has, off, 64);
    }
    if (tid == 0) {
      float lig = atomicAdd(&ws[0], 0.f) * (1.f / 64.f);
      float sc_mse = atomicAdd(&ws[3], 0.f);
      float sc_am = atomicAdd(&ws[4], 0.f);
      float sc_val = atomicAdd(&ws[5], 0.f);
      float sc_has = atomicAdd(&ws[6], 0.f);
      float ligand_dist_loss = val / fmaxf(has, 1.f);
      float sidechain_loss = sc_mse / fmaxf(sc_am, 1.f);
      float sidechain_dist_loss = sc_val / fmaxf(sc_has, 1.f);
      out[0] = lig + 0.2f * ligand_dist_loss + 0.5f * sidechain_loss +
               0.1f * sidechain_dist_loss;
    }
  }
}

extern "C" void kernel_launch(void* const* d_in, const int* in_sizes, int n_in,
                              void* d_out, int out_size, void* d_ws, size_t ws_size,
                              hipStream_t stream) {
  const float* ligand_pred = (const float*)d_in[0];
  const float* ligand_tgt = (const float*)d_in[1];
  const float* sidechain_pred = (const float*)d_in[2];
  const float* sidechain_tgt = (const float*)d_in[3];
  const int* ligand_mask = (const int*)d_in[4];
  const int* atom_mask = (const int*)d_in[5];
  float* out = (float*)d_out;
  float* ws = (float*)d_ws;

  hipMemsetAsync(ws, 0, 136 * sizeof(float), stream);  // accumulators + counter
  fused_kernel<<<GRID, 256, 0, stream>>>(ligand_pred, ligand_tgt, ligand_mask,
                                         sidechain_pred, sidechain_tgt, atom_mask,
                                         ws, out);
}

// Round 10
// 104.641 us; speedup vs baseline: 1.3302x; 1.3302x over previous
//
#include <hip/hip_runtime.h>

#define CUTOFF 5.0f
#define DEPS 1e-12f
#define FSQRT(x) __builtin_amdgcn_sqrtf(x)

// ws float layout (every slot written unconditionally every launch):
//  [0, 1024)     lig_part[512][2]  (num, den) per ligand block (triangular: half of ref sums)
//  [1024, 1088)  lig_coord[64]     per-batch coord ratio (t==0 blocks)
//  [1088, 3136)  sc_part[512][4]   (mse, am, val, has) per sidechain block

#define NSC_BLK 512   // blocks [0,512): sidechain, 128 groups each (2 lanes/group)
#define NLIG_BLK 512  // blocks [512,1024): ligand, 64 batches * 8 balanced tile-pairs
#define GRID (NSC_BLK + NLIG_BLK)

// one pair evaluation: dist(tgt_i, tgt_j) vs dist(pred_i, pred_j), weight w
#define PAIR_EVAL(ti, pi, tjx, tjy, tjz, pjx, pjy, pjz, w, numv, denv)    \
  {                                                                       \
    float dx = (ti).x - (tjx), dy = (ti).y - (tjy), dz = (ti).z - (tjz);  \
    float tsq = dx * dx + dy * dy + dz * dz;                              \
    float td = FSQRT(fmaxf(tsq, DEPS));                                   \
    float ww = (w);                                                       \
    ww = (tsq > 0.f) ? ww : 0.f;                                          \
    ww = (td <= CUTOFF) ? ww : 0.f;                                       \
    float qx = (pi).x - (pjx), qy = (pi).y - (pjy), qz = (pi).z - (pjz);  \
    float pd = FSQRT(fmaxf(qx * qx + qy * qy + qz * qz, DEPS));           \
    float dd = pd - td;                                                   \
    numv += ww * dd * dd;                                                 \
    denv += ww;                                                           \
  }

__global__ __launch_bounds__(256) void fused_kernel(
    const float* __restrict__ lig_pred, const float* __restrict__ lig_tgt,
    const int* __restrict__ lig_mask,
    const float* __restrict__ sc_pred, const float* __restrict__ sc_tgt,
    const int* __restrict__ sc_mask,
    float* __restrict__ ws) {
  const int tid = threadIdx.x;
  __shared__ float4 stage4[1344];  // 21.5 KB; sc staging / ligand i-tiles (aliased)
  __shared__ float red[4][4];

  if (blockIdx.x < NSC_BLK) {
    // ================= sidechain: 2 lanes per group (R4/R5/R7 path, verified) =================
    const int sb = blockIdx.x;
    float ax[7], ay[7], az[7];  // pred, own atoms
    float bx[7], by[7], bz[7];  // tgt, own atoms
    float m[7];

    const float4* srcp = (const float4*)(sc_pred + (size_t)sb * 5376);
    for (int k = tid; k < 1344; k += 256) stage4[k] = srcp[k];
    __syncthreads();
    {
      const float* s = ((const float*)stage4) + tid * 21;  // gcd(21,32)=1: no conflicts
#pragma unroll
      for (int a = 0; a < 7; a++) { ax[a] = s[3 * a]; ay[a] = s[3 * a + 1]; az[a] = s[3 * a + 2]; }
    }
    __syncthreads();
    const float4* srct = (const float4*)(sc_tgt + (size_t)sb * 5376);
    for (int k = tid; k < 1344; k += 256) stage4[k] = srct[k];
    __syncthreads();
    {
      const float* s = ((const float*)stage4) + tid * 21;
#pragma unroll
      for (int a = 0; a < 7; a++) { bx[a] = s[3 * a]; by[a] = s[3 * a + 1]; bz[a] = s[3 * a + 2]; }
    }
    const int* mp = sc_mask + (size_t)sb * 1792 + tid * 7;
#pragma unroll
    for (int a = 0; a < 7; a++) m[a] = (mp[a] != 0) ? 1.f : 0.f;

    float mse = 0.f, am = 0.f;
#pragma unroll
    for (int a = 0; a < 7; a++) {
      float dx = ax[a] - bx[a], dy = ay[a] - by[a], dz = az[a] - bz[a];
      mse += m[a] * ((dx * dx + dy * dy + dz * dz) * (1.f / 3.f));
      am += m[a];
    }

    float num = 0.f, den = 0.f;
#pragma unroll
    for (int js = 0; js < 7; js++) {
#pragma unroll
      for (int side = 0; side < 2; side++) {
        float jx, jy, jz, kx, ky, kz, mj;
        if (side == 0) {
          jx = ax[js]; jy = ay[js]; jz = az[js];
          kx = bx[js]; ky = by[js]; kz = bz[js];
          mj = m[js];
        } else {
          jx = __shfl_xor(ax[js], 1, 64); jy = __shfl_xor(ay[js], 1, 64);
          jz = __shfl_xor(az[js], 1, 64);
          kx = __shfl_xor(bx[js], 1, 64); ky = __shfl_xor(by[js], 1, 64);
          kz = __shfl_xor(bz[js], 1, 64);
          mj = __shfl_xor(m[js], 1, 64);
        }
#pragma unroll
        for (int i = 0; i < 7; i++) {
          float dx = bx[i] - kx, dy = by[i] - ky, dz = bz[i] - kz;
          float tsq = dx * dx + dy * dy + dz * dz;
          float td = FSQRT(fmaxf(tsq, DEPS));
          float w = m[i] * mj;
          w = (tsq > 0.f) ? w : 0.f;
          w = (td <= CUTOFF) ? w : 0.f;
          float qx = ax[i] - jx, qy = ay[i] - jy, qz = az[i] - jz;
          float pd = FSQRT(fmaxf(qx * qx + qy * qy + qz * qz, DEPS));
          float d = pd - td;
          num += w * d * d;
          den += w;
        }
      }
    }
    float num_g = num + __shfl_xor(num, 1, 64);
    float den_g = den + __shfl_xor(den, 1, 64);
    float val = (den_g > 0.f) ? 0.5f * (num_g / fmaxf(den_g, 1.f)) : 0.f;
    float has = (den_g > 0.f) ? 0.5f : 0.f;

    for (int off = 32; off > 0; off >>= 1) {
      mse += __shfl_down(mse, off, 64);
      am += __shfl_down(am, off, 64);
      val += __shfl_down(val, off, 64);
      has += __shfl_down(has, off, 64);
    }
    int lane = tid & 63, wv = tid >> 6;
    if (lane == 0) { red[0][wv] = mse; red[1][wv] = am; red[2][wv] = val; red[3][wv] = has; }
    __syncthreads();
    if (tid == 0) {
      float* p = ws + 1088 + (size_t)sb * 4;
      p[0] = red[0][0] + red[0][1] + red[0][2] + red[0][3];
      p[1] = red[1][0] + red[1][1] + red[1][2] + red[1][3];
      p[2] = red[2][0] + red[2][1] + red[2][2] + red[2][3];
      p[3] = red[3][0] + red[3][1] + red[3][2] + red[3][3];
    }
  } else {
    // ====== ligand: triangular, balanced tile-pairs {t,15-t}, 3 fused j-slots ======
    // Slot A0: j = i0a+tid          (always valid; gate j>i <=> tid>ii)
    // Slot A1: j = i0a+256+tid      (valid iff j<512; triangular gate always true)
    // Slot B : j = i0b+tid          (valid iff j<512; gate tid>ii)
    // Same covered pair set as R7 (verified); invalid slots predicated w=0.
    const int L = 512;
    const int lb = blockIdx.x - NSC_BLK;  // 0..511
    const int b = lb >> 3;
    const int t = lb & 7;
    const int i0a = 32 * t;
    const int i0b = 32 * (15 - t);
    const float* pb = lig_pred + (size_t)b * L * 3;
    const float* tb = lig_tgt + (size_t)b * L * 3;
    const int* mb = lig_mask + (size_t)b * L;

    float4* st4 = stage4;       // [0,32): tileA tgt(+mask), [32,64): tileB tgt(+mask)
    float4* sp4 = stage4 + 64;  // [0,32): tileA pred,       [32,64): tileB pred

    if (tid < 128) {
      int which = tid >> 5;  // 0: A-tgt, 1: B-tgt, 2: A-pred, 3: B-pred
      int idx = tid & 31;
      int i = ((which & 1) ? i0b : i0a) + idx;
      if (which < 2) {
        st4[(which << 5) + idx] =
            make_float4(tb[3 * i], tb[3 * i + 1], tb[3 * i + 2], (mb[i] != 0) ? 1.f : 0.f);
      } else {
        sp4[((which & 1) << 5) + idx] =
            make_float4(pb[3 * i], pb[3 * i + 1], pb[3 * i + 2], 0.f);
      }
    }

    // j-point loads (overlap with staging; barrier below covers both)
    const int jA0 = i0a + tid;
    const int jA1r = i0a + 256 + tid;
    const int jA1 = jA1r & (L - 1);  // clamp into bounds; weight zeroed if invalid
    const int jBr = i0b + tid;
    const int jB = jBr & (L - 1);

    float pA0x = pb[3 * jA0], pA0y = pb[3 * jA0 + 1], pA0z = pb[3 * jA0 + 2];
    float tA0x = tb[3 * jA0], tA0y = tb[3 * jA0 + 1], tA0z = tb[3 * jA0 + 2];
    float mA0 = (mb[jA0] != 0) ? 1.f : 0.f;
    float pA1x = pb[3 * jA1], pA1y = pb[3 * jA1 + 1], pA1z = pb[3 * jA1 + 2];
    float tA1x = tb[3 * jA1], tA1y = tb[3 * jA1 + 1], tA1z = tb[3 * jA1 + 2];
    float mA1 = (jA1r < L && mb[jA1] != 0) ? 1.f : 0.f;
    float pBx = pb[3 * jB], pBy = pb[3 * jB + 1], pBz = pb[3 * jB + 2];
    float tBx = tb[3 * jB], tBy = tb[3 * jB + 1], tBz = tb[3 * jB + 2];
    float mB = (jBr < L && mb[jB] != 0) ? 1.f : 0.f;

    float se = 0.f, cnt = 0.f;
    if (t == 0) {  // A0 (j=tid) + A1 (j=256+tid, all valid at t==0) cover all 512 atoms
      float dx = pA0x - tA0x, dy = pA0y - tA0y, dz = pA0z - tA0z;
      se += mA0 * (dx * dx + dy * dy + dz * dz);
      cnt += mA0;
      dx = pA1x - tA1x; dy = pA1y - tA1y; dz = pA1z - tA1z;
      se += mA1 * (dx * dx + dy * dy + dz * dz);
      cnt += mA1;
    }
    __syncthreads();

    // num,den accumulate exactly HALF of the reference's symmetric sums.
    float nA0 = 0.f, dA0 = 0.f, nA1 = 0.f, dA1 = 0.f, nB = 0.f, dB = 0.f;
#pragma unroll 8
    for (int ii = 0; ii < 32; ii++) {
      float4 tiA = st4[ii];       // wave-uniform -> broadcast ds_read_b128
      float4 piA = sp4[ii];
      float4 tiB = st4[32 + ii];
      float4 piB = sp4[32 + ii];
      float wA0 = (tid > ii) ? tiA.w * mA0 : 0.f;
      PAIR_EVAL(tiA, piA, tA0x, tA0y, tA0z, pA0x, pA0y, pA0z, wA0, nA0, dA0);
      float wA1 = tiA.w * mA1;  // triangular gate provably true for this slot
      PAIR_EVAL(tiA, piA, tA1x, tA1y, tA1z, pA1x, pA1y, pA1z, wA1, nA1, dA1);
      float wB = (tid > ii) ? tiB.w * mB : 0.f;
      PAIR_EVAL(tiB, piB, tBx, tBy, tBz, pBx, pBy, pBz, wB, nB, dB);
    }

    float num = nA0 + nA1 + nB, den = dA0 + dA1 + dB;
    for (int off = 32; off > 0; off >>= 1) {
      num += __shfl_down(num, off, 64);
      den += __shfl_down(den, off, 64);
      se += __shfl_down(se, off, 64);
      cnt += __shfl_down(cnt, off, 64);
    }
    int lane = tid & 63, wv = tid >> 6;
    if (lane == 0) { red[0][wv] = num; red[1][wv] = den; red[2][wv] = se; red[3][wv] = cnt; }
    __syncthreads();
    if (tid == 0) {
      ws[lb * 2 + 0] = red[0][0] + red[0][1] + red[0][2] + red[0][3];
      ws[lb * 2 + 1] = red[1][0] + red[1][1] + red[1][2] + red[1][3];
      if (t == 0) {
        float se_t = red[2][0] + red[2][1] + red[2][2] + red[2][3];
        float cnt_t = red[3][0] + red[3][1] + red[3][2] + red[3][3];
        ws[1024 + b] = se_t / (3.f * fmaxf(cnt_t, 1.f));
      }
    }
  }
}

__global__ __launch_bounds__(256) void finalize_kernel(const float* __restrict__ ws,
                                                       float* __restrict__ out) {
  const int tid = threadIdx.x;
  __shared__ float sred[4][4];

  const float* sc = ws + 1088;
  float s0 = 0.f, s1 = 0.f, s2 = 0.f, s3 = 0.f;
  for (int i = tid; i < 512; i += 256) {
    s0 += sc[4 * i + 0]; s1 += sc[4 * i + 1]; s2 += sc[4 * i + 2]; s3 += sc[4 * i + 3];
  }
  for (int off = 32; off > 0; off >>= 1) {
    s0 += __shfl_down(s0, off, 64);
    s1 += __shfl_down(s1, off, 64);
    s2 += __shfl_down(s2, off, 64);
    s3 += __shfl_down(s3, off, 64);
  }
  int lane = tid & 63, wv = tid >> 6;
  if (lane == 0) { sred[0][wv] = s0; sred[1][wv] = s1; sred[2][wv] = s2; sred[3][wv] = s3; }
  __syncthreads();

  float lval = 0.f, lhas = 0.f, lcoord = 0.f;
  if (tid < 64) {
    float n = 0.f, d = 0.f;
    for (int t = 0; t < 8; t++) {
      n += ws[(tid * 8 + t) * 2 + 0];
      d += ws[(tid * 8 + t) * 2 + 1];
    }
    lval = (d > 0.f) ? n / fmaxf(d, 1.f) : 0.f;
    lhas = (d > 0.f) ? 1.f : 0.f;
    lcoord = ws[1024 + tid];
    for (int off = 32; off > 0; off >>= 1) {
      lval += __shfl_down(lval, off, 64);
      lhas += __shfl_down(lhas, off, 64);
      lcoord += __shfl_down(lcoord, off, 64);
    }
  }
  if (tid == 0) {
    float sc_mse = sred[0][0] + sred[0][1] + sred[0][2] + sred[0][3];
    float sc_am = sred[1][0] + sred[1][1] + sred[1][2] + sred[1][3];
    float sc_val = sred[2][0] + sred[2][1] + sred[2][2] + sred[2][3];
    float sc_has = sred[3][0] + sred[3][1] + sred[3][2] + sred[3][3];
    float ligand_loss = lcoord * (1.f / 64.f);
    float ligand_dist_loss = lval / fmaxf(lhas, 1.f);
    float sidechain_loss = sc_mse / fmaxf(sc_am, 1.f);
    float sidechain_dist_loss = sc_val / fmaxf(sc_has, 1.f);
    out[0] = ligand_loss + 0.2f * ligand_dist_loss + 0.5f * sidechain_loss +
             0.1f * sidechain_dist_loss;
  }
}

extern "C" void kernel_launch(void* const* d_in, const int* in_sizes, int n_in,
                              void* d_out, int out_size, void* d_ws, size_t ws_size,
                              hipStream_t stream) {
  const float* ligand_pred = (const float*)d_in[0];
  const float* ligand_tgt = (const float*)d_in[1];
  const float* sidechain_pred = (const float*)d_in[2];
  const float* sidechain_tgt = (const float*)d_in[3];
  const int* ligand_mask = (const int*)d_in[4];
  const int* atom_mask = (const int*)d_in[5];
  float* out = (float*)d_out;
  float* ws = (float*)d_ws;

  fused_kernel<<<GRID, 256, 0, stream>>>(ligand_pred, ligand_tgt, ligand_mask,
                                         sidechain_pred, sidechain_tgt, atom_mask, ws);
  finalize_kernel<<<1, 256, 0, stream>>>(ws, out);
}